// Round 1
// 1623.039 us; speedup vs baseline: 1.1479x; 1.1479x over previous
//
#include <hip/hip_runtime.h>

typedef unsigned short u16;
typedef short s16x8 __attribute__((ext_vector_type(8)));
typedef float f32x4 __attribute__((ext_vector_type(4)));

__device__ __forceinline__ float u2f(u16 u) {
    union { unsigned int i; float f; } c; c.i = ((unsigned int)u) << 16; return c.f;
}
__device__ __forceinline__ u16 f2u(float f) {
    union { float f; unsigned int i; } c; c.f = f;
    unsigned int x = c.i;
    x += 0x7fffu + ((x >> 16) & 1u);   // RNE
    return (u16)(x >> 16);
}

// ---------------------------------------------------------------------------
// Generic 3x3 SAME conv as 9 tap-GEMM K-slabs, MFMA 16x16x32 bf16.
// (legacy single-buffer kernel; still used for head conv and seg convs)
// ---------------------------------------------------------------------------
template<int BN, int WMW, int WNW, int WSHIFT>
__global__ __launch_bounds__(256, 2)
void conv3x3_mfma(const u16* __restrict__ in, const u16* __restrict__ wT,
                  const float* __restrict__ bias, u16* __restrict__ out,
                  int Cin, int Cout, int Npad, int Wp, int in_img_stride,
                  int tiles_per_img, int xtiles,
                  int ldC, int out_rstride, int out_istride, int out_off,
                  int KC, int relu)
{
    constexpr int WT_    = 1 << WSHIFT;   // cols per M-tile
    constexpr int WMROWS = 128 / WMW;     // rows of C per wave (m)
    constexpr int WNCOLS = BN / WNW;      // cols of C per wave (n)
    constexpr int AM     = WMROWS / 16;
    constexpr int AN     = WNCOLS / 16;
    constexpr int BINSTR = (BN * 64) / 1024;  // 1KB B-chunks

    __shared__ __align__(16) u16 As[128 * 32];
    __shared__ __align__(16) u16 Bs[BN * 32];

    const int tid  = threadIdx.x;
    const int wave = tid >> 6;
    const int lane = tid & 63;
    const int l15  = lane & 15;
    const int quad = lane >> 4;
    const int wm   = wave / WNW;
    const int wn   = wave % WNW;

    const int tile  = blockIdx.x;
    const int n0    = blockIdx.y * BN;
    const int img   = tile / tiles_per_img;
    const int rem   = tile - img * tiles_per_img;
    const int ytile = rem / xtiles;
    const int xt    = rem - ytile * xtiles;
    const int RT    = 128 / WT_;
    const int y0    = ytile * RT;
    const int x0    = xt * WT_;

    // A staging: 8 x 1KB chunks; wave w does chunks {w, w+4}
    const u16* aptr[2];
#pragma unroll
    for (int s = 0; s < 2; ++s) {
        int p = wave + s * 4;
        int e = p * 512 + lane * 8;      // element index in [128][32] tile
        int m = e >> 5;
        int c = e & 31;
        int ry = m >> WSHIFT;
        int xcol = m & (WT_ - 1);
        aptr[s] = in + (long)img * in_img_stride
                     + ((y0 + ry) * Wp + (x0 + xcol)) * Cin + c;
    }
    // B staging: BINSTR x 1KB chunks
    const u16* bptr[2];
    {
        int s = 0;
        for (int q = wave; q < BINSTR; q += 4, ++s) {
            int e = q * 512 + lane * 8;  // element in [BN][32] tile
            int n = e >> 5;
            int k = e & 31;
            bptr[s] = wT + (n0 + n) * Cin + k;
        }
    }

    f32x4 acc[AM][AN];
#pragma unroll
    for (int i = 0; i < AM; ++i)
#pragma unroll
        for (int j = 0; j < AN; ++j) acc[i][j] = {0.f, 0.f, 0.f, 0.f};

    for (int tap = 0; tap < 9; ++tap) {
        const int dy = tap / 3, dx = tap - dy * 3;
        const int aoff_tap = (dy * Wp + dx) * Cin;
        const int boff_tap = tap * Npad * Cin;
        for (int kc = 0; kc < KC; ++kc) {
            const int coff = kc * 32;
#pragma unroll
            for (int s = 0; s < 2; ++s) {
                __builtin_amdgcn_global_load_lds(
                    (const __attribute__((address_space(1))) void*)(aptr[s] + aoff_tap + coff),
                    (__attribute__((address_space(3))) void*)(&As[(wave + s * 4) * 512]),
                    16, 0, 0);
            }
            {
                int s = 0;
                for (int q = wave; q < BINSTR; q += 4, ++s) {
                    __builtin_amdgcn_global_load_lds(
                        (const __attribute__((address_space(1))) void*)(bptr[s] + boff_tap + coff),
                        (__attribute__((address_space(3))) void*)(&Bs[q * 512]),
                        16, 0, 0);
                }
            }
            __syncthreads();

            s16x8 af[AM], bf[AN];
#pragma unroll
            for (int i = 0; i < AM; ++i)
                af[i] = *(const s16x8*)&As[(wm * WMROWS + i * 16 + l15) * 32 + quad * 8];
#pragma unroll
            for (int j = 0; j < AN; ++j)
                bf[j] = *(const s16x8*)&Bs[(wn * WNCOLS + j * 16 + l15) * 32 + quad * 8];
#pragma unroll
            for (int i = 0; i < AM; ++i)
#pragma unroll
                for (int j = 0; j < AN; ++j)
                    acc[i][j] = __builtin_amdgcn_mfma_f32_16x16x32_bf16(
                        af[i], bf[j], acc[i][j], 0, 0, 0);
            __syncthreads();
        }
    }

    // epilogue: C/D layout col=lane&15, row=quad*4+r  (m89/m91-verified)
    const long obase = (long)out_off + (long)img * out_istride;
#pragma unroll
    for (int i = 0; i < AM; ++i) {
        int mb = wm * WMROWS + i * 16 + quad * 4;
#pragma unroll
        for (int j = 0; j < AN; ++j) {
            int n = n0 + wn * WNCOLS + j * 16 + l15;
            if (n < Cout) {
                float bv = bias[n];
#pragma unroll
                for (int r = 0; r < 4; ++r) {
                    int m = mb + r;
                    int ry = m >> WSHIFT, xcol = m & (WT_ - 1);
                    float v = acc[i][j][r] + bv;
                    if (relu) v = fmaxf(v, 0.f);
                    out[obase + (long)(y0 + ry) * out_rstride + (long)(x0 + xcol) * ldC + n] = f2u(v);
                }
            }
        }
    }
}

// ---------------------------------------------------------------------------
// 8-phase double-buffered conv (cb1/cb2: Cout==256 only).
// BM=256 positions (256>>WSHIFT rows x 1<<WSHIFT cols), BN=256, BK=64.
// 512 thr = 8 waves (2M x 4N); per-wave C = 128x64 -> acc[8][4].
// LDS 128KB: A slots 2x32KB @0, B slots 2x32KB @64KB.
// Half-tiles interleaved by quadrant:
//   A half h: C-rows r with ((r>>6)&1)==h   (lrow = (r&63) + 64*(r>>7))
//   B half h: C-cols c with ((c>>5)&1)==h   (lcol = (c&31) + 32*(c>>6))
// T2 swizzle: byte ^= (lrow&7)<<4 on ds_read; staging keeps LDS dest linear
// and pre-swizzles the GLOBAL source channel-slot (rule #21).
// Schedule per K-tile u (slot s=u&1, staging tile u+1 into s^1):
//   q0: read Aa,Ba | stage Aa' | vmcnt(4) bar | mfma quad(0,0) | bar
//   q1: read Bb    | stage Ba' | vmcnt(4) bar | mfma quad(0,1) | bar
//   q2: read Ab    | stage Bb' |          bar | mfma quad(1,0) | bar
//   q3:            | stage Ab' | vmcnt(4) bar | mfma quad(1,1) | bar
// vmcnt(4) == 2 half-tiles (2 loads each, per wave) always in flight.
// ---------------------------------------------------------------------------
template<int MQ, int NQ>
__device__ __forceinline__ void mfma_quad(f32x4 (&acc)[8][4], const s16x8 (&aR)[4][2],
                                          const s16x8 (&bR)[2][2])
{
#pragma unroll
    for (int i = 0; i < 4; ++i)
#pragma unroll
        for (int j = 0; j < 2; ++j)
#pragma unroll
            for (int k = 0; k < 2; ++k)
                acc[MQ * 4 + i][NQ * 2 + j] = __builtin_amdgcn_mfma_f32_16x16x32_bf16(
                    aR[i][k], bR[j][k], acc[MQ * 4 + i][NQ * 2 + j], 0, 0, 0);
}

#define BAR() asm volatile("s_barrier" ::: "memory")
#define VMW(n) asm volatile("s_waitcnt vmcnt(" #n ")" ::: "memory")

#define STG_A(slot, h, off) do { \
    __builtin_amdgcn_global_load_lds( \
        (const __attribute__((address_space(1))) void*)(aptrA[h][0] + (off)), \
        (__attribute__((address_space(3))) void*)(&lds[((slot) * 32768 + (h) * 16384 + wave * 1024) >> 1]), \
        16, 0, 0); \
    __builtin_amdgcn_global_load_lds( \
        (const __attribute__((address_space(1))) void*)(aptrA[h][1] + (off)), \
        (__attribute__((address_space(3))) void*)(&lds[((slot) * 32768 + (h) * 16384 + 8192 + wave * 1024) >> 1]), \
        16, 0, 0); \
} while (0)

#define STG_B(slot, h, off) do { \
    __builtin_amdgcn_global_load_lds( \
        (const __attribute__((address_space(1))) void*)(bptrB[h][0] + (off)), \
        (__attribute__((address_space(3))) void*)(&lds[(65536 + (slot) * 32768 + (h) * 16384 + wave * 1024) >> 1]), \
        16, 0, 0); \
    __builtin_amdgcn_global_load_lds( \
        (const __attribute__((address_space(1))) void*)(bptrB[h][1] + (off)), \
        (__attribute__((address_space(3))) void*)(&lds[(65536 + (slot) * 32768 + (h) * 16384 + 8192 + wave * 1024) >> 1]), \
        16, 0, 0); \
} while (0)

#define LDA_HALF(dst, soff, mq) do { \
    const int _ab = (soff) + (mq) * 16384 + arow; \
    _Pragma("unroll") \
    for (int _i = 0; _i < 4; ++_i) { \
        dst[_i][0] = *(const s16x8*)&lds[(_ab + _i * 2048 + cS0) >> 1]; \
        dst[_i][1] = *(const s16x8*)&lds[(_ab + _i * 2048 + cS1) >> 1]; \
    } \
} while (0)

#define LDB_HALF(dst, soff, nq) do { \
    const int _bb = 65536 + (soff) + (nq) * 16384 + brow; \
    _Pragma("unroll") \
    for (int _j = 0; _j < 2; ++_j) { \
        dst[_j][0] = *(const s16x8*)&lds[(_bb + _j * 2048 + cS0) >> 1]; \
        dst[_j][1] = *(const s16x8*)&lds[(_bb + _j * 2048 + cS1) >> 1]; \
    } \
} while (0)

template<int KC2, int WSHIFT>
__global__ __launch_bounds__(512, 2)
void conv3x3_8ph(const u16* __restrict__ in, const u16* __restrict__ wT,
                 const float* __restrict__ bias, u16* __restrict__ out,
                 int Cin, int Wp, long in_img_stride,
                 int tiles_per_img, int xtiles,
                 int ldC, int out_rstride, long out_istride, long out_off,
                 int relu)
{
    constexpr int WT_  = 1 << WSHIFT;
    constexpr int ROWS = 256 >> WSHIFT;
    constexpr int T    = 9 * KC2;          // K-tiles of 64 channels

    __shared__ __align__(16) u16 lds[65536];   // 128 KB

    const int tid  = threadIdx.x;
    const int wave = tid >> 6;
    const int lane = tid & 63;
    const int l15  = lane & 15;
    const int quad = lane >> 4;
    const int wm   = wave >> 2;            // 0..1
    const int wn   = wave & 3;             // 0..3
    const int x7   = l15 & 7;
    const int cS0  = (quad ^ x7) << 4;           // ksub 0 slot (swizzled)
    const int cS1  = ((quad | 4) ^ x7) << 4;     // ksub 1 slot
    const int arow = (l15 + wm * 64) * 128;
    const int brow = (l15 + wn * 32) * 128;

    // XCD-aware swizzle (gridDim.x % 8 == 0 by construction)
    const int nwg = gridDim.x;
    const int b0  = blockIdx.x;
    const int bid = (b0 & 7) * (nwg >> 3) + (b0 >> 3);

    const int img   = bid / tiles_per_img;
    const int rem   = bid - img * tiles_per_img;
    const int ytile = rem / xtiles;
    const int xt    = rem - ytile * xtiles;
    const int y0    = ytile * ROWS;
    const int x0    = xt * WT_;

    // per-thread staging source pointers (pre-swizzled channel slot)
    const u16* aptrA[2][2];
    const u16* bptrB[2][2];
    {
        const int lr0  = tid >> 3;      // 0..63
        const int s16v = tid & 7;
#pragma unroll
        for (int h = 0; h < 2; ++h)
#pragma unroll
            for (int r = 0; r < 2; ++r) {
                int lrow = r * 64 + lr0;
                int srcc = (s16v ^ (lrow & 7)) << 3;
                int rowA = lrow + (lrow & 64) + h * 64;
                int ry = rowA >> WSHIFT, xcol = rowA & (WT_ - 1);
                aptrA[h][r] = in + (long)img * in_img_stride
                            + ((long)(y0 + ry) * Wp + (x0 + xcol)) * Cin + srcc;
                int col = ((lrow >> 5) << 6) + h * 32 + (lrow & 31);
                bptrB[h][r] = wT + (long)col * Cin + srcc;
            }
    }

    f32x4 acc[8][4];
#pragma unroll
    for (int i = 0; i < 8; ++i)
#pragma unroll
        for (int j = 0; j < 4; ++j) acc[i][j] = {0.f, 0.f, 0.f, 0.f};

    // K-tile -> (tap, kc) offsets
    auto aoff_of = [&](int v) -> long {
        int tap = v / KC2, kc = v - tap * KC2;
        int dy = tap / 3, dx = tap - dy * 3;
        return (long)(dy * Wp + dx) * Cin + kc * 64;
    };
    auto boff_of = [&](int v) -> long {
        int tap = v / KC2, kc = v - tap * KC2;
        return (long)tap * 256 * Cin + kc * 64;
    };

    // prologue: stage tile 0 (Aa, Ba, Bb, Ab order)
    STG_A(0, 0, 0);
    STG_B(0, 0, 0);
    STG_B(0, 1, 0);
    STG_A(0, 1, 0);
    VMW(4); BAR();

    s16x8 aR[4][2], bA[2][2], bB[2][2];

    for (int u = 0; u < T - 1; ++u) {
        const int s = (u & 1) * 32768;
        const int t = (u + 1) & 1;
        const long aN = aoff_of(u + 1);
        const long bN = boff_of(u + 1);
        // q0
        LDA_HALF(aR, s, 0);
        LDB_HALF(bA, s, 0);
        STG_A(t, 0, aN);
        VMW(4); BAR();
        __builtin_amdgcn_s_setprio(1);
        mfma_quad<0, 0>(acc, aR, bA);
        __builtin_amdgcn_s_setprio(0);
        BAR();
        // q1
        LDB_HALF(bB, s, 1);
        STG_B(t, 0, bN);
        VMW(4); BAR();
        __builtin_amdgcn_s_setprio(1);
        mfma_quad<0, 1>(acc, aR, bB);
        __builtin_amdgcn_s_setprio(0);
        BAR();
        // q2
        LDA_HALF(aR, s, 1);
        STG_B(t, 1, bN);
        BAR();
        __builtin_amdgcn_s_setprio(1);
        mfma_quad<1, 0>(acc, aR, bA);
        __builtin_amdgcn_s_setprio(0);
        BAR();
        // q3
        STG_A(t, 1, aN);
        VMW(4); BAR();
        __builtin_amdgcn_s_setprio(1);
        mfma_quad<1, 1>(acc, aR, bB);
        __builtin_amdgcn_s_setprio(0);
        BAR();
    }
    // tail tile (no staging)
    {
        const int s = ((T - 1) & 1) * 32768;
        LDA_HALF(aR, s, 0);
        LDB_HALF(bA, s, 0);
        VMW(2); BAR();                       // Bb now landed
        __builtin_amdgcn_s_setprio(1);
        mfma_quad<0, 0>(acc, aR, bA);
        __builtin_amdgcn_s_setprio(0);
        LDB_HALF(bB, s, 1);
        VMW(0); BAR();                       // Ab landed
        mfma_quad<0, 1>(acc, aR, bB);
        LDA_HALF(aR, s, 1);
        mfma_quad<1, 0>(acc, aR, bA);
        mfma_quad<1, 1>(acc, aR, bB);
    }

    // epilogue
    const long obase = out_off + (long)img * out_istride;
#pragma unroll
    for (int mi = 0; mi < 8; ++mi) {
        const int mbase = wm * 128 + mi * 16 + quad * 4;
#pragma unroll
        for (int nj = 0; nj < 4; ++nj) {
            const int n = wn * 64 + nj * 16 + l15;
            const float bv = bias[n];
#pragma unroll
            for (int r = 0; r < 4; ++r) {
                int m = mbase + r;
                int ry = m >> WSHIFT, xcol = m & (WT_ - 1);
                float v = acc[mi][nj][r] + bv;
                if (relu) v = fmaxf(v, 0.f);
                out[obase + (long)(y0 + ry) * out_rstride + (long)(x0 + xcol) * ldC + n] = f2u(v);
            }
        }
    }
}

#undef BAR
#undef VMW
#undef STG_A
#undef STG_B
#undef LDA_HALF
#undef LDB_HALF

// ---------------------------------------------------------------------------
// zero only the 1-px padding ring of an NHWC-padded buffer
// ---------------------------------------------------------------------------
__global__ void zero_ring(u16* __restrict__ buf, int Hp, int Wp, int C,
                          long img_stride, int per, long tot)
{
    long idx = (long)blockIdx.x * 256 + threadIdx.x;
    if (idx >= tot) return;
    int img = (int)(idx / per);
    int r = (int)(idx - (long)img * per);
    int pos = r / C;
    int c = r - pos * C;
    long off;
    if (pos < Wp)            off = (long)pos * C;
    else if (pos < 2 * Wp)   off = ((long)(Hp - 1) * Wp + (pos - Wp)) * C;
    else {
        int p2 = pos - 2 * Wp;
        int row = 1 + (p2 >> 1);
        off = ((long)row * Wp + ((p2 & 1) ? (Wp - 1) : 0)) * C;
    }
    buf[(long)img * img_stride + off + c] = 0;
}

// ---------------------------------------------------------------------------
// weight transpose+cvt: w fp32 [3,3,Cin,Cout] -> wT bf16 [9][Npad][Cin]
// ---------------------------------------------------------------------------
__global__ void transpose_w(const float* __restrict__ w, u16* __restrict__ wT,
                            int Cin, int Cout, int Npad)
{
    int idx = blockIdx.x * 256 + threadIdx.x;
    int total = 9 * Npad * Cin;
    if (idx >= total) return;
    int cin = idx % Cin;
    int r = idx / Cin;
    int n = r % Npad;
    int tap = r / Npad;
    wT[idx] = (n < Cout) ? f2u(w[(tap * Cin + cin) * Cout + n]) : (u16)0;
}

// combined reg(12) + wt(3) + zero(1) head weights -> bf16 [9][16][256], fp32 bias16
__global__ void transpose_head(const float* __restrict__ regw, const float* __restrict__ wtw,
                               const float* __restrict__ regb, const float* __restrict__ wtb,
                               u16* __restrict__ wT, float* __restrict__ bOut)
{
    int idx = blockIdx.x * 256 + threadIdx.x;
    if (idx < 16)
        bOut[idx] = (idx < 12) ? regb[idx] : (idx < 15 ? wtb[idx - 12] : 0.f);
    if (idx >= 9 * 16 * 256) return;
    int cin = idx & 255;
    int r = idx >> 8;
    int n = r & 15;
    int tap = r >> 4;
    float v = 0.f;
    if (n < 12)      v = regw[(tap * 256 + cin) * 12 + n];
    else if (n < 15) v = wtw[(tap * 256 + cin) * 3 + (n - 12)];
    wT[idx] = f2u(v);
}

// feat1 fp32 [4,256,256,128] -> bf16 pad1 [4,258,258,128] interior
__global__ void cvt_pad(const float* __restrict__ in, u16* __restrict__ out)
{
    int idx = blockIdx.x * 256 + threadIdx.x;  // 4*256*256*16 chunks of 8ch
    if (idx >= 4 * 256 * 256 * 16) return;
    int cc = idx & 15;
    int pos = idx >> 4;
    int x = pos & 255, y = (pos >> 8) & 255, b = pos >> 16;
    const float4* s4 = (const float4*)(in + (size_t)idx * 8);
    float4 a = s4[0], bb = s4[1];
    u16 tmp[8];
    tmp[0] = f2u(a.x);  tmp[1] = f2u(a.y);  tmp[2] = f2u(a.z);  tmp[3] = f2u(a.w);
    tmp[4] = f2u(bb.x); tmp[5] = f2u(bb.y); tmp[6] = f2u(bb.z); tmp[7] = f2u(bb.w);
    *(uint4*)&out[(((b * 258 + y + 1) * 258) + x + 1) * 128 + cc * 8] = *(uint4*)tmp;
}

// classification head: mean -> fc1 -> fc2 -> fc3 -> softmax/argmax  (all fp32)
__global__ __launch_bounds__(256)
void cls_head(const float* __restrict__ feat5,
              const float* fc1w, const float* fc1b,
              const float* fc2w, const float* fc2b,
              const float* fc3w, const float* fc3b,
              float* __restrict__ pred_out, int* __restrict__ cls_out)
{
    int b = blockIdx.x, t = threadIdx.x;
    __shared__ float g[256], h1[256], h2[256], lg[3];
    const float* base = feat5 + b * 65536;
    float s = 0.f;
    for (int p = 0; p < 256; ++p) s += base[p * 256 + t];
    g[t] = s * (1.f / 256.f);
    __syncthreads();
    float a = fc1b[t];
    for (int k = 0; k < 256; ++k) a += g[k] * fc1w[k * 256 + t];
    h1[t] = fmaxf(a, 0.f);
    __syncthreads();
    a = fc2b[t];
    for (int k = 0; k < 256; ++k) a += h1[k] * fc2w[k * 256 + t];
    h2[t] = fmaxf(a, 0.f);
    __syncthreads();
    if (t < 3) {
        float l = fc3b[t];
        for (int k = 0; k < 256; ++k) l += h2[k] * fc3w[k * 3 + t];
        lg[t] = l;
    }
    __syncthreads();
    if (t == 0) {
        float m = fmaxf(lg[0], fmaxf(lg[1], lg[2]));
        float e0 = expf(lg[0] - m), e1 = expf(lg[1] - m), e2 = expf(lg[2] - m);
        float inv = 1.f / (e0 + e1 + e2);
        pred_out[b * 3 + 0] = e0 * inv;
        pred_out[b * 3 + 1] = e1 * inv;
        pred_out[b * 3 + 2] = e2 * inv;
        int best = 0;
        if (lg[1] > lg[best]) best = 1;
        if (lg[2] > lg[best]) best = 2;
        cls_out[b] = best;
    }
}

// bilinear crop: fp32 feat0 [4,512,512,64] + fp32 boxes -> bf16 cropsp [256][34][34][64]
__global__ __launch_bounds__(256)
void crop_kernel(const float* __restrict__ feat0, const float* __restrict__ boxes,
                 u16* __restrict__ cropsp)
{
    int gid = blockIdx.x;           // n*32 + oy
    int oy = gid & 31;
    int n = gid >> 5;
    int b = n >> 6;
    const float* bx = boxes + n * 4;
    float y1 = bx[0], x1 = bx[1], y2 = bx[2], x2 = bx[3];
    float ty = (float)oy * (1.f / 31.f);
    float ys = y1 * 511.f + (ty * (y2 - y1)) * 511.f;
    int y0i = (int)floorf(ys);
    y0i = y0i < 0 ? 0 : (y0i > 510 ? 510 : y0i);
    float wy = ys - (float)y0i;
    int t = threadIdx.x;
    int c = t & 63;
    int xg = t >> 6;
    const float* r0 = feat0 + ((size_t)(b * 512 + y0i) * 512) * 64;
    for (int ox = xg; ox < 32; ox += 4) {
        float tx = (float)ox * (1.f / 31.f);
        float xs = x1 * 511.f + (tx * (x2 - x1)) * 511.f;
        int x0i = (int)floorf(xs);
        x0i = x0i < 0 ? 0 : (x0i > 510 ? 510 : x0i);
        float wx = xs - (float)x0i;
        float v00 = r0[x0i * 64 + c];
        float v01 = r0[(x0i + 1) * 64 + c];
        float v10 = r0[32768 + x0i * 64 + c];
        float v11 = r0[32768 + (x0i + 1) * 64 + c];
        float ca = v00 * (1.f - wy) + v10 * wy;
        float cb = v01 * (1.f - wy) + v11 * wy;
        float val = ca * (1.f - wx) + cb * wx;
        cropsp[((n * 34 + oy + 1) * 34 + ox + 1) * 64 + c] = f2u(val);
    }
}

// per-class gather of bf16 reg/wt head -> fp32 offsets, sizes, weights
__global__ void reg_gather(const u16* __restrict__ head15, const int* __restrict__ cls,
                           float* __restrict__ out)
{
    int idx = blockIdx.x * 256 + threadIdx.x;   // 4*256*256
    if (idx >= 262144) return;
    int b = idx >> 16;
    int cl = cls[b];
    int c4 = cl * 4;
    const u16* p = head15 + (long)idx * 16;
    out[idx * 2 + 0] = u2f(p[c4]);
    out[idx * 2 + 1] = u2f(p[c4 + 1]);
    out[524288 + idx * 2 + 0] = u2f(p[c4 + 2]);
    out[524288 + idx * 2 + 1] = u2f(p[c4 + 3]);
    out[1048576 + idx] = u2f(p[12 + cl]);
}

__global__ void seg_gather(const u16* __restrict__ seg16, const int* __restrict__ cls,
                           float* __restrict__ out)
{
    int idx = blockIdx.x * 256 + threadIdx.x;   // 256*32*32
    if (idx >= 262144) return;
    int n = idx >> 10;
    out[idx] = u2f(seg16[(long)idx * 16 + cls[n >> 6]]);
}

// score head: 4x4 avgpool(bf16 s2p) -> fp32 fc 6144->256 -> 256->256 -> 256->3 -> select
__global__ __launch_bounds__(256)
void score_head(const u16* __restrict__ s2p,
                const float* sd1w, const float* sd1b,
                const float* sd2w, const float* sd2b,
                const float* sd3w, const float* sd3b,
                const int* __restrict__ cls, float* __restrict__ out)
{
    int n = blockIdx.x, t = threadIdx.x;
    __shared__ float pooled[6144];
    __shared__ float h1[256], h2[256];
    const u16* sb = s2p + (long)n * 34 * 34 * 96;
    for (int q = 0; q < 24; ++q) {
        int o = t + 256 * q;
        int c = o % 96;
        int pw = o / 96;
        int wx = pw & 7, hy = pw >> 3;
        float s = 0.f;
        for (int i = 0; i < 4; ++i)
            for (int j = 0; j < 4; ++j)
                s += u2f(sb[((1 + hy * 4 + i) * 34 + (1 + wx * 4 + j)) * 96 + c]);
        pooled[o] = s * 0.0625f;
    }
    __syncthreads();
    float a = sd1b[t];
    for (int k = 0; k < 6144; ++k) a += pooled[k] * sd1w[k * 256 + t];
    h1[t] = fmaxf(a, 0.f);
    __syncthreads();
    a = sd2b[t];
    for (int k = 0; k < 256; ++k) a += h1[k] * sd2w[k * 256 + t];
    h2[t] = fmaxf(a, 0.f);
    __syncthreads();
    if (t == 0) {
        int cl = cls[n >> 6];
        float s = sd3b[cl];
        for (int k = 0; k < 256; ++k) s += h2[k] * sd3w[k * 3 + cl];
        out[n] = s;
    }
}

// ---------------------------------------------------------------------------
extern "C" void kernel_launch(void* const* d_in, const int* in_sizes, int n_in,
                              void* d_out, int out_size, void* d_ws, size_t ws_size,
                              hipStream_t stream)
{
    const float* feat0 = (const float*)d_in[0];
    const float* feat1 = (const float*)d_in[1];
    const float* feat5 = (const float*)d_in[2];
    const float* boxes = (const float*)d_in[3];
    const float* cb1_w = (const float*)d_in[4];  const float* cb1_b = (const float*)d_in[5];
    const float* cb2_w = (const float*)d_in[6];  const float* cb2_b = (const float*)d_in[7];
    const float* reg_w = (const float*)d_in[8];  const float* reg_b = (const float*)d_in[9];
    const float* wt_w  = (const float*)d_in[10]; const float* wt_b  = (const float*)d_in[11];
    const float* fc1_w = (const float*)d_in[12]; const float* fc1_b = (const float*)d_in[13];
    const float* fc2_w = (const float*)d_in[14]; const float* fc2_b = (const float*)d_in[15];
    const float* fc3_w = (const float*)d_in[16]; const float* fc3_b = (const float*)d_in[17];
    const float* sc1_w = (const float*)d_in[18]; const float* sc1_b = (const float*)d_in[19];
    const float* sc2_w = (const float*)d_in[20]; const float* sc2_b = (const float*)d_in[21];
    const float* so_w  = (const float*)d_in[22]; const float* so_b  = (const float*)d_in[23];
    const float* sd1_w = (const float*)d_in[24]; const float* sd1_b = (const float*)d_in[25];
    const float* sd2_w = (const float*)d_in[26]; const float* sd2_b = (const float*)d_in[27];
    const float* sd3_w = (const float*)d_in[28]; const float* sd3_b = (const float*)d_in[29];

    char* ws = (char*)d_ws;
    size_t off = 0;
    auto alloc = [&](size_t bytes) -> char* {
        char* p = ws + off;
        off += (bytes + 255) & ~(size_t)255;
        return p;
    };
    u16* pad1   = (u16*)alloc(68161536);   // region0: later reused as cropsp
    u16* x1p    = (u16*)alloc(136323072);  // region1: later reused as s1p+s2p
    u16* x2p    = (u16*)alloc(136323072);
    u16* head15 = (u16*)alloc(8388608);
    u16* seg16  = (u16*)alloc(8388608);
    u16* cb1T   = (u16*)alloc(589824);
    u16* cb2T   = (u16*)alloc(1179648);
    u16* headT  = (u16*)alloc(73728);
    float* headB = (float*)alloc(64);
    u16* sc1T   = (u16*)alloc(147456);
    u16* sc2T   = (u16*)alloc(221184);
    u16* soT    = (u16*)alloc(27648);
    int* cls    = (int*)alloc(16);
    u16* cropsp = pad1;                    // 37,879,808 B <= 68,161,536
    u16* s1p    = x1p;                     // 56,819,712 B
    u16* s2p    = x1p + 28409856;          // + 56,819,712 B (fits region1)
    float* d_o  = (float*)d_out;

    auto ring = [&](u16* buf, int n, int Hp, int Wp, int C) {
        int per = (2 * Wp + 2 * (Hp - 2)) * C;
        long tot = (long)per * n;
        zero_ring<<<(int)((tot + 255) / 256), 256, 0, stream>>>(
            buf, Hp, Wp, C, (long)Hp * Wp * C, per, tot);
    };

    // weight transposes (tiny)
    transpose_w<<<(9*256*128 + 255)/256, 256, 0, stream>>>(cb1_w, cb1T, 128, 256, 256);
    transpose_w<<<(9*256*256 + 255)/256, 256, 0, stream>>>(cb2_w, cb2T, 256, 256, 256);
    transpose_w<<<(9*128*64  + 255)/256, 256, 0, stream>>>(sc1_w, sc1T, 64, 96, 128);
    transpose_w<<<(9*128*96  + 255)/256, 256, 0, stream>>>(sc2_w, sc2T, 96, 96, 128);
    transpose_w<<<(9*16*96   + 255)/256, 256, 0, stream>>>(so_w,  soT,  96, 3, 16);
    transpose_head<<<(9*16*256 + 255)/256, 256, 0, stream>>>(reg_w, wt_w, reg_b, wt_b, headT, headB);

    // classification branch (also produces cls[] used by all gathers)
    cls_head<<<4, 256, 0, stream>>>(feat5, fc1_w, fc1_b, fc2_w, fc2_b, fc3_w, fc3_b,
                                    d_o + 1310720, cls);

    // regression branch
    ring(pad1, 4, 258, 258, 128);
    cvt_pad<<<16384, 256, 0, stream>>>(feat1, pad1);
    ring(x1p, 4, 258, 258, 256);
    conv3x3_8ph<2, 7><<<1024, 512, 0, stream>>>(
        pad1, cb1T, cb1_b, x1p, 128, 258, 258L*258*128, 256, 2,
        256, 258*256, 258L*258*256, 259*256, 1);
    ring(x2p, 4, 258, 258, 256);
    conv3x3_8ph<4, 7><<<1024, 512, 0, stream>>>(
        x1p, cb2T, cb2_b, x2p, 256, 258, 258L*258*256, 256, 2,
        256, 258*256, 258L*258*256, 259*256, 1);
    conv3x3_mfma<16,4,1,7><<<dim3(2048,1), 256, 0, stream>>>(
        x2p, headT, headB, head15, 256, 15, 16, 258, 258*258*256, 512, 2,
        16, 256*16, 256*256*16, 0, 8, 0);
    reg_gather<<<1024, 256, 0, stream>>>(head15, cls, d_o);

    // segmentation branch (reuses region0/region1 after convs above)
    ring(cropsp, 256, 34, 34, 64);
    crop_kernel<<<8192, 256, 0, stream>>>(feat0, boxes, cropsp);
    ring(s1p, 256, 34, 34, 96);
    conv3x3_mfma<128,2,2,5><<<dim3(2048,1), 256, 0, stream>>>(
        cropsp, sc1T, sc1_b, s1p, 64, 96, 128, 34, 34*34*64, 8, 1,
        96, 34*96, 34*34*96, 35*96, 2, 1);
    ring(s2p, 256, 34, 34, 96);
    conv3x3_mfma<128,2,2,5><<<dim3(2048,1), 256, 0, stream>>>(
        s1p, sc2T, sc2_b, s2p, 96, 96, 128, 34, 34*34*96, 8, 1,
        96, 34*96, 34*34*96, 35*96, 3, 1);
    conv3x3_mfma<16,4,1,5><<<dim3(2048,1), 256, 0, stream>>>(
        s2p, soT, so_b, seg16, 96, 3, 16, 34, 34*34*96, 8, 1,
        16, 32*16, 32*32*16, 0, 3, 0);
    seg_gather<<<1024, 256, 0, stream>>>(seg16, cls, d_o + 1310732);
    score_head<<<256, 256, 0, stream>>>(s2p, sd1_w, sd1_b, sd2_w, sd2_b, sd3_w, sd3_b,
                                        cls, d_o + 1572876);
    (void)in_sizes; (void)n_in; (void)out_size; (void)ws_size;
}

// Round 3
// 1482.972 us; speedup vs baseline: 1.2563x; 1.0944x over previous
//
#include <hip/hip_runtime.h>

typedef unsigned short u16;
typedef short s16x8 __attribute__((ext_vector_type(8)));
typedef float f32x4 __attribute__((ext_vector_type(4)));

__device__ __forceinline__ float u2f(u16 u) {
    union { unsigned int i; float f; } c; c.i = ((unsigned int)u) << 16; return c.f;
}
__device__ __forceinline__ u16 f2u(float f) {
    union { float f; unsigned int i; } c; c.f = f;
    unsigned int x = c.i;
    x += 0x7fffu + ((x >> 16) & 1u);   // RNE
    return (u16)(x >> 16);
}

// ---------------------------------------------------------------------------
// Generic 3x3 SAME conv as 9 tap-GEMM K-slabs, MFMA 16x16x32 bf16.
// (legacy single-buffer kernel; still used for seg convs sc1/sc2)
// ---------------------------------------------------------------------------
template<int BN, int WMW, int WNW, int WSHIFT>
__global__ __launch_bounds__(256, 2)
void conv3x3_mfma(const u16* __restrict__ in, const u16* __restrict__ wT,
                  const float* __restrict__ bias, u16* __restrict__ out,
                  int Cin, int Cout, int Npad, int Wp, int in_img_stride,
                  int tiles_per_img, int xtiles,
                  int ldC, int out_rstride, int out_istride, int out_off,
                  int KC, int relu)
{
    constexpr int WT_    = 1 << WSHIFT;   // cols per M-tile
    constexpr int WMROWS = 128 / WMW;     // rows of C per wave (m)
    constexpr int WNCOLS = BN / WNW;      // cols of C per wave (n)
    constexpr int AM     = WMROWS / 16;
    constexpr int AN     = WNCOLS / 16;
    constexpr int BINSTR = (BN * 64) / 1024;  // 1KB B-chunks

    __shared__ __align__(16) u16 As[128 * 32];
    __shared__ __align__(16) u16 Bs[BN * 32];

    const int tid  = threadIdx.x;
    const int wave = tid >> 6;
    const int lane = tid & 63;
    const int l15  = lane & 15;
    const int quad = lane >> 4;
    const int wm   = wave / WNW;
    const int wn   = wave % WNW;

    const int tile  = blockIdx.x;
    const int n0    = blockIdx.y * BN;
    const int img   = tile / tiles_per_img;
    const int rem   = tile - img * tiles_per_img;
    const int ytile = rem / xtiles;
    const int xt    = rem - ytile * xtiles;
    const int RT    = 128 / WT_;
    const int y0    = ytile * RT;
    const int x0    = xt * WT_;

    // A staging: 8 x 1KB chunks; wave w does chunks {w, w+4}
    const u16* aptr[2];
#pragma unroll
    for (int s = 0; s < 2; ++s) {
        int p = wave + s * 4;
        int e = p * 512 + lane * 8;      // element index in [128][32] tile
        int m = e >> 5;
        int c = e & 31;
        int ry = m >> WSHIFT;
        int xcol = m & (WT_ - 1);
        aptr[s] = in + (long)img * in_img_stride
                     + ((y0 + ry) * Wp + (x0 + xcol)) * Cin + c;
    }
    // B staging: BINSTR x 1KB chunks
    const u16* bptr[2];
    {
        int s = 0;
        for (int q = wave; q < BINSTR; q += 4, ++s) {
            int e = q * 512 + lane * 8;  // element in [BN][32] tile
            int n = e >> 5;
            int k = e & 31;
            bptr[s] = wT + (n0 + n) * Cin + k;
        }
    }

    f32x4 acc[AM][AN];
#pragma unroll
    for (int i = 0; i < AM; ++i)
#pragma unroll
        for (int j = 0; j < AN; ++j) acc[i][j] = {0.f, 0.f, 0.f, 0.f};

    for (int tap = 0; tap < 9; ++tap) {
        const int dy = tap / 3, dx = tap - dy * 3;
        const int aoff_tap = (dy * Wp + dx) * Cin;
        const int boff_tap = tap * Npad * Cin;
        for (int kc = 0; kc < KC; ++kc) {
            const int coff = kc * 32;
#pragma unroll
            for (int s = 0; s < 2; ++s) {
                __builtin_amdgcn_global_load_lds(
                    (const __attribute__((address_space(1))) void*)(aptr[s] + aoff_tap + coff),
                    (__attribute__((address_space(3))) void*)(&As[(wave + s * 4) * 512]),
                    16, 0, 0);
            }
            {
                int s = 0;
                for (int q = wave; q < BINSTR; q += 4, ++s) {
                    __builtin_amdgcn_global_load_lds(
                        (const __attribute__((address_space(1))) void*)(bptr[s] + boff_tap + coff),
                        (__attribute__((address_space(3))) void*)(&Bs[q * 512]),
                        16, 0, 0);
                }
            }
            __syncthreads();

            s16x8 af[AM], bf[AN];
#pragma unroll
            for (int i = 0; i < AM; ++i)
                af[i] = *(const s16x8*)&As[(wm * WMROWS + i * 16 + l15) * 32 + quad * 8];
#pragma unroll
            for (int j = 0; j < AN; ++j)
                bf[j] = *(const s16x8*)&Bs[(wn * WNCOLS + j * 16 + l15) * 32 + quad * 8];
#pragma unroll
            for (int i = 0; i < AM; ++i)
#pragma unroll
                for (int j = 0; j < AN; ++j)
                    acc[i][j] = __builtin_amdgcn_mfma_f32_16x16x32_bf16(
                        af[i], bf[j], acc[i][j], 0, 0, 0);
            __syncthreads();
        }
    }

    // epilogue: C/D layout col=lane&15, row=quad*4+r  (m89/m91-verified)
    const long obase = (long)out_off + (long)img * out_istride;
#pragma unroll
    for (int i = 0; i < AM; ++i) {
        int mb = wm * WMROWS + i * 16 + quad * 4;
#pragma unroll
        for (int j = 0; j < AN; ++j) {
            int n = n0 + wn * WNCOLS + j * 16 + l15;
            if (n < Cout) {
                float bv = bias[n];
#pragma unroll
                for (int r = 0; r < 4; ++r) {
                    int m = mb + r;
                    int ry = m >> WSHIFT, xcol = m & (WT_ - 1);
                    float v = acc[i][j][r] + bv;
                    if (relu) v = fmaxf(v, 0.f);
                    out[obase + (long)(y0 + ry) * out_rstride + (long)(x0 + xcol) * ldC + n] = f2u(v);
                }
            }
        }
    }
}

// ---------------------------------------------------------------------------
// 8-phase double-buffered conv (cb1/cb2: Cout==256 only).  (unchanged, R1)
// ---------------------------------------------------------------------------
template<int MQ, int NQ>
__device__ __forceinline__ void mfma_quad(f32x4 (&acc)[8][4], const s16x8 (&aR)[4][2],
                                          const s16x8 (&bR)[2][2])
{
#pragma unroll
    for (int i = 0; i < 4; ++i)
#pragma unroll
        for (int j = 0; j < 2; ++j)
#pragma unroll
            for (int k = 0; k < 2; ++k)
                acc[MQ * 4 + i][NQ * 2 + j] = __builtin_amdgcn_mfma_f32_16x16x32_bf16(
                    aR[i][k], bR[j][k], acc[MQ * 4 + i][NQ * 2 + j], 0, 0, 0);
}

#define BAR() asm volatile("s_barrier" ::: "memory")
#define VMW(n) asm volatile("s_waitcnt vmcnt(" #n ")" ::: "memory")

#define STG_A(slot, h, off) do { \
    __builtin_amdgcn_global_load_lds( \
        (const __attribute__((address_space(1))) void*)(aptrA[h][0] + (off)), \
        (__attribute__((address_space(3))) void*)(&lds[((slot) * 32768 + (h) * 16384 + wave * 1024) >> 1]), \
        16, 0, 0); \
    __builtin_amdgcn_global_load_lds( \
        (const __attribute__((address_space(1))) void*)(aptrA[h][1] + (off)), \
        (__attribute__((address_space(3))) void*)(&lds[((slot) * 32768 + (h) * 16384 + 8192 + wave * 1024) >> 1]), \
        16, 0, 0); \
} while (0)

#define STG_B(slot, h, off) do { \
    __builtin_amdgcn_global_load_lds( \
        (const __attribute__((address_space(1))) void*)(bptrB[h][0] + (off)), \
        (__attribute__((address_space(3))) void*)(&lds[(65536 + (slot) * 32768 + (h) * 16384 + wave * 1024) >> 1]), \
        16, 0, 0); \
    __builtin_amdgcn_global_load_lds( \
        (const __attribute__((address_space(1))) void*)(bptrB[h][1] + (off)), \
        (__attribute__((address_space(3))) void*)(&lds[(65536 + (slot) * 32768 + (h) * 16384 + 8192 + wave * 1024) >> 1]), \
        16, 0, 0); \
} while (0)

#define LDA_HALF(dst, soff, mq) do { \
    const int _ab = (soff) + (mq) * 16384 + arow; \
    _Pragma("unroll") \
    for (int _i = 0; _i < 4; ++_i) { \
        dst[_i][0] = *(const s16x8*)&lds[(_ab + _i * 2048 + cS0) >> 1]; \
        dst[_i][1] = *(const s16x8*)&lds[(_ab + _i * 2048 + cS1) >> 1]; \
    } \
} while (0)

#define LDB_HALF(dst, soff, nq) do { \
    const int _bb = 65536 + (soff) + (nq) * 16384 + brow; \
    _Pragma("unroll") \
    for (int _j = 0; _j < 2; ++_j) { \
        dst[_j][0] = *(const s16x8*)&lds[(_bb + _j * 2048 + cS0) >> 1]; \
        dst[_j][1] = *(const s16x8*)&lds[(_bb + _j * 2048 + cS1) >> 1]; \
    } \
} while (0)

template<int KC2, int WSHIFT>
__global__ __launch_bounds__(512, 2)
void conv3x3_8ph(const u16* __restrict__ in, const u16* __restrict__ wT,
                 const float* __restrict__ bias, u16* __restrict__ out,
                 int Cin, int Wp, long in_img_stride,
                 int tiles_per_img, int xtiles,
                 int ldC, int out_rstride, long out_istride, long out_off,
                 int relu)
{
    constexpr int WT_  = 1 << WSHIFT;
    constexpr int ROWS = 256 >> WSHIFT;
    constexpr int T    = 9 * KC2;          // K-tiles of 64 channels

    __shared__ __align__(16) u16 lds[65536];   // 128 KB

    const int tid  = threadIdx.x;
    const int wave = tid >> 6;
    const int lane = tid & 63;
    const int l15  = lane & 15;
    const int quad = lane >> 4;
    const int wm   = wave >> 2;            // 0..1
    const int wn   = wave & 3;             // 0..3
    const int x7   = l15 & 7;
    const int cS0  = (quad ^ x7) << 4;           // ksub 0 slot (swizzled)
    const int cS1  = ((quad | 4) ^ x7) << 4;     // ksub 1 slot
    const int arow = (l15 + wm * 64) * 128;
    const int brow = (l15 + wn * 32) * 128;

    // XCD-aware swizzle (gridDim.x % 8 == 0 by construction)
    const int nwg = gridDim.x;
    const int b0  = blockIdx.x;
    const int bid = (b0 & 7) * (nwg >> 3) + (b0 >> 3);

    const int img   = bid / tiles_per_img;
    const int rem   = bid - img * tiles_per_img;
    const int ytile = rem / xtiles;
    const int xt    = rem - ytile * xtiles;
    const int y0    = ytile * ROWS;
    const int x0    = xt * WT_;

    // per-thread staging source pointers (pre-swizzled channel slot)
    const u16* aptrA[2][2];
    const u16* bptrB[2][2];
    {
        const int lr0  = tid >> 3;      // 0..63
        const int s16v = tid & 7;
#pragma unroll
        for (int h = 0; h < 2; ++h)
#pragma unroll
            for (int r = 0; r < 2; ++r) {
                int lrow = r * 64 + lr0;
                int srcc = (s16v ^ (lrow & 7)) << 3;
                int rowA = lrow + (lrow & 64) + h * 64;
                int ry = rowA >> WSHIFT, xcol = rowA & (WT_ - 1);
                aptrA[h][r] = in + (long)img * in_img_stride
                            + ((long)(y0 + ry) * Wp + (x0 + xcol)) * Cin + srcc;
                int col = ((lrow >> 5) << 6) + h * 32 + (lrow & 31);
                bptrB[h][r] = wT + (long)col * Cin + srcc;
            }
    }

    f32x4 acc[8][4];
#pragma unroll
    for (int i = 0; i < 8; ++i)
#pragma unroll
        for (int j = 0; j < 4; ++j) acc[i][j] = {0.f, 0.f, 0.f, 0.f};

    // K-tile -> (tap, kc) offsets
    auto aoff_of = [&](int v) -> long {
        int tap = v / KC2, kc = v - tap * KC2;
        int dy = tap / 3, dx = tap - dy * 3;
        return (long)(dy * Wp + dx) * Cin + kc * 64;
    };
    auto boff_of = [&](int v) -> long {
        int tap = v / KC2, kc = v - tap * KC2;
        return (long)tap * 256 * Cin + kc * 64;
    };

    // prologue: stage tile 0 (Aa, Ba, Bb, Ab order)
    STG_A(0, 0, 0);
    STG_B(0, 0, 0);
    STG_B(0, 1, 0);
    STG_A(0, 1, 0);
    VMW(4); BAR();

    s16x8 aR[4][2], bA[2][2], bB[2][2];

    for (int u = 0; u < T - 1; ++u) {
        const int s = (u & 1) * 32768;
        const int t = (u + 1) & 1;
        const long aN = aoff_of(u + 1);
        const long bN = boff_of(u + 1);
        // q0
        LDA_HALF(aR, s, 0);
        LDB_HALF(bA, s, 0);
        STG_A(t, 0, aN);
        VMW(4); BAR();
        __builtin_amdgcn_s_setprio(1);
        mfma_quad<0, 0>(acc, aR, bA);
        __builtin_amdgcn_s_setprio(0);
        BAR();
        // q1
        LDB_HALF(bB, s, 1);
        STG_B(t, 0, bN);
        VMW(4); BAR();
        __builtin_amdgcn_s_setprio(1);
        mfma_quad<0, 1>(acc, aR, bB);
        __builtin_amdgcn_s_setprio(0);
        BAR();
        // q2
        LDA_HALF(aR, s, 1);
        STG_B(t, 1, bN);
        BAR();
        __builtin_amdgcn_s_setprio(1);
        mfma_quad<1, 0>(acc, aR, bA);
        __builtin_amdgcn_s_setprio(0);
        BAR();
        // q3
        STG_A(t, 1, aN);
        VMW(4); BAR();
        __builtin_amdgcn_s_setprio(1);
        mfma_quad<1, 1>(acc, aR, bB);
        __builtin_amdgcn_s_setprio(0);
        BAR();
    }
    // tail tile (no staging)
    {
        const int s = ((T - 1) & 1) * 32768;
        LDA_HALF(aR, s, 0);
        LDB_HALF(bA, s, 0);
        VMW(2); BAR();                       // Bb now landed
        __builtin_amdgcn_s_setprio(1);
        mfma_quad<0, 0>(acc, aR, bA);
        __builtin_amdgcn_s_setprio(0);
        LDB_HALF(bB, s, 1);
        VMW(0); BAR();                       // Ab landed
        mfma_quad<0, 1>(acc, aR, bB);
        LDA_HALF(aR, s, 1);
        mfma_quad<1, 0>(acc, aR, bA);
        mfma_quad<1, 1>(acc, aR, bB);
    }

    // epilogue
    const long obase = out_off + (long)img * out_istride;
#pragma unroll
    for (int mi = 0; mi < 8; ++mi) {
        const int mbase = wm * 128 + mi * 16 + quad * 4;
#pragma unroll
        for (int nj = 0; nj < 4; ++nj) {
            const int n = wn * 64 + nj * 16 + l15;
            const float bv = bias[n];
#pragma unroll
            for (int r = 0; r < 4; ++r) {
                int m = mbase + r;
                int ry = m >> WSHIFT, xcol = m & (WT_ - 1);
                float v = acc[mi][nj][r] + bv;
                if (relu) v = fmaxf(v, 0.f);
                out[obase + (long)(y0 + ry) * out_rstride + (long)(x0 + xcol) * ldC + n] = f2u(v);
            }
        }
    }
}

#undef STG_A
#undef STG_B
#undef LDA_HALF
#undef LDB_HALF

// ---------------------------------------------------------------------------
// Small-N 3x3 conv (Cout<=16): B fully LDS-resident, A halo staged once per
// 32-ch chunk and reused across all 9 taps (4.4x HBM traffic cut vs legacy).
// 256 thr = 4 waves; per wave 64 positions x 16 outputs -> acc[4] f32x4.
// Tile = TR rows x TC cols (TR*TC==256). Halo = (TR+2)x(TC+2) x 32ch.
// Halo staged as 28 chunks of 1KB (7/wave), double-buffered (2x28KB).
// A swizzle: LDS slot sl at position p holds ch-chunk sl^(p&3); reader wants
// chunk=quad -> reads slot quad^(p&3) (rule #21: linear LDS dest, inverse-
// swizzled global src). B pre-swizzled at transpose time: [tap][n][slot]
// holds ch-chunk slot^(n&7); reader reads slot (kc*4+quad)^(n&7) -> 2-way free.
// ---------------------------------------------------------------------------
#define GLL(src, dst) __builtin_amdgcn_global_load_lds( \
    (const __attribute__((address_space(1))) void*)(src), \
    (__attribute__((address_space(3))) void*)(dst), 16, 0, 0)

template<int TR, int TC, int CIN, int CINB, int NKC>
__global__ __launch_bounds__(256, 1)
void conv3x3_n16(const u16* __restrict__ in, const u16* __restrict__ wTs,
                 const float* __restrict__ bias, u16* __restrict__ out,
                 long in_img_stride, int Wp, int tiles_per_img, int xtiles,
                 long out_istride, int out_rstride)
{
    constexpr int HC  = TC + 2;
    constexpr int NB  = (9 * 16 * CINB * 2) / 1024;   // 1KB B chunks
    constexpr int XSH = (TC == 64) ? 6 : 5;
    static_assert((TR + 2) * HC <= 448, "halo must fit 28 chunks");

    __shared__ __align__(16) u16 Bs[9 * 16 * CINB];
    __shared__ __align__(16) u16 halo[28672];          // 2 x 28KB

    const int tid  = threadIdx.x;
    const int wave = tid >> 6;
    const int lane = tid & 63;
    const int l15  = lane & 15;
    const int quad = lane >> 4;

    const int bid   = blockIdx.x;
    const int img   = bid / tiles_per_img;
    const int rem   = bid - img * tiles_per_img;
    const int ytile = rem / xtiles;
    const int xt    = rem - ytile * xtiles;
    const int gy0   = ytile * TR;
    const int gx0   = xt * TC;

    const u16* inb = in + (long)img * in_img_stride;

    // stage B (whole swizzled weight block) into LDS
    for (int i = wave; i < NB; i += 4)
        GLL(wTs + i * 512 + lane * 8, &Bs[i * 512]);

    // halo chunk per-thread source pointers (7 chunks per wave, clamped pads)
    const u16* hsrc[7];
#pragma unroll
    for (int i = 0; i < 7; ++i) {
        int c  = wave + 4 * i;
        int o  = c * 1024 + lane * 16;    // byte offset in halo image
        int p  = o >> 6;                   // halo position (64B each)
        int sl = (o >> 4) & 3;             // 16B slot within position
        int c8 = sl ^ (p & 3);             // source ch-chunk (pre-swizzle)
        int hr = p / HC; if (hr > TR + 1) hr = TR + 1;
        int hx = p - hr * HC; if (hx > TC + 1) hx = TC + 1;
        hsrc[i] = inb + ((long)(gy0 + hr) * Wp + (gx0 + hx)) * CIN + c8 * 8;
    }

    f32x4 acc[4];
#pragma unroll
    for (int mf = 0; mf < 4; ++mf) acc[mf] = {0.f, 0.f, 0.f, 0.f};

    int pb[4];
#pragma unroll
    for (int mf = 0; mf < 4; ++mf) {
        int m  = wave * 64 + mf * 16 + l15;
        pb[mf] = (m >> XSH) * HC + (m & (TC - 1));
    }

    // prologue: stage chunk 0 into slot 0
#pragma unroll
    for (int i = 0; i < 7; ++i)
        GLL(hsrc[i], &halo[(wave + 4 * i) * 512]);
    asm volatile("s_waitcnt vmcnt(0)" ::: "memory");
    __syncthreads();

    for (int kc = 0; kc < NKC; ++kc) {
        if (kc + 1 < NKC) {
            const int off = (kc + 1) * 32;                 // ch offset (u16)
            const int ds  = ((kc + 1) & 1) * 14336;
#pragma unroll
            for (int i = 0; i < 7; ++i)
                GLL(hsrc[i] + off, &halo[ds + (wave + 4 * i) * 512]);
        }
        const int so_ = (kc & 1) * 14336;
        const int cs4 = kc * 4 + quad;
#pragma unroll
        for (int tap = 0; tap < 9; ++tap) {
            const int dy = tap / 3, dx = tap - dy * 3;
            s16x8 bf = *(const s16x8*)&Bs[(tap * 16 + l15) * CINB
                                          + ((cs4 ^ (l15 & 7)) << 3)];
#pragma unroll
            for (int mf = 0; mf < 4; ++mf) {
                int p = pb[mf] + dy * HC + dx;
                s16x8 af = *(const s16x8*)&halo[so_ + p * 32
                                                + ((quad ^ (p & 3)) << 3)];
                acc[mf] = __builtin_amdgcn_mfma_f32_16x16x32_bf16(
                    af, bf, acc[mf], 0, 0, 0);
            }
        }
        asm volatile("s_waitcnt vmcnt(0)" ::: "memory");
        __syncthreads();
    }

    // epilogue: col=l15 (n), row=quad*4+r
    const long obase = (long)img * out_istride;
    const float bv = bias[l15];
#pragma unroll
    for (int mf = 0; mf < 4; ++mf) {
#pragma unroll
        for (int r = 0; r < 4; ++r) {
            int m  = wave * 64 + mf * 16 + quad * 4 + r;
            int ry = m >> XSH, xc = m & (TC - 1);
            out[obase + (long)(gy0 + ry) * out_rstride + (long)(gx0 + xc) * 16 + l15] =
                f2u(acc[mf][r] + bv);
        }
    }
}

#undef GLL
#undef BAR
#undef VMW

// ---------------------------------------------------------------------------
// zero only the 1-px padding ring of an NHWC-padded buffer
// ---------------------------------------------------------------------------
__global__ void zero_ring(u16* __restrict__ buf, int Hp, int Wp, int C,
                          long img_stride, int per, long tot)
{
    long idx = (long)blockIdx.x * 256 + threadIdx.x;
    if (idx >= tot) return;
    int img = (int)(idx / per);
    int r = (int)(idx - (long)img * per);
    int pos = r / C;
    int c = r - pos * C;
    long off;
    if (pos < Wp)            off = (long)pos * C;
    else if (pos < 2 * Wp)   off = ((long)(Hp - 1) * Wp + (pos - Wp)) * C;
    else {
        int p2 = pos - 2 * Wp;
        int row = 1 + (p2 >> 1);
        off = ((long)row * Wp + ((p2 & 1) ? (Wp - 1) : 0)) * C;
    }
    buf[(long)img * img_stride + off + c] = 0;
}

// ---------------------------------------------------------------------------
// weight transpose+cvt: w fp32 [3,3,Cin,Cout] -> wT bf16 [9][Npad][Cin]
// (used by cb1/cb2/sc1/sc2)
// ---------------------------------------------------------------------------
__global__ void transpose_w(const float* __restrict__ w, u16* __restrict__ wT,
                            int Cin, int Cout, int Npad)
{
    int idx = blockIdx.x * 256 + threadIdx.x;
    int total = 9 * Npad * Cin;
    if (idx >= total) return;
    int cin = idx % Cin;
    int r = idx / Cin;
    int n = r % Npad;
    int tap = r / Npad;
    wT[idx] = (n < Cout) ? f2u(w[(tap * Cin + cin) * Cout + n]) : (u16)0;
}

// swizzled small-N weights: out[tap][n][slot][j] = w[(tap*Cin+ch)*Nout+n],
// ch = (slot^(n&7))*8+j, zero-padded; also emits padded fp32 bias16.
template<int CINB>
__global__ void transpose_n16_swz(const float* __restrict__ w1,
                                  const float* __restrict__ w2,
                                  const float* __restrict__ b1,
                                  const float* __restrict__ b2,
                                  u16* __restrict__ wTs, float* __restrict__ bOut,
                                  int Cin, int n1, int n2)
{
    int idx = blockIdx.x * 256 + threadIdx.x;
    if (idx < 16 && blockIdx.x == 0)
        bOut[idx] = (idx < n1) ? b1[idx] : (idx < n1 + n2 ? b2[idx - n1] : 0.f);
    if (idx >= 9 * 16 * CINB) return;
    constexpr int SL = CINB / 8;
    int j    = idx & 7;
    int r    = idx >> 3;
    int slot = r & (SL - 1);
    int r2   = r / SL;
    int n    = r2 & 15;
    int tap  = r2 >> 4;
    int ch   = (slot ^ (n & 7)) * 8 + j;
    float v = 0.f;
    if (ch < Cin) {
        if (n < n1)           v = w1[(tap * Cin + ch) * n1 + n];
        else if (n < n1 + n2) v = w2[(tap * Cin + ch) * n2 + (n - n1)];
    }
    wTs[idx] = f2u(v);
}

// feat1 fp32 [4,256,256,128] -> bf16 pad1 [4,258,258,128] interior
__global__ void cvt_pad(const float* __restrict__ in, u16* __restrict__ out)
{
    int idx = blockIdx.x * 256 + threadIdx.x;  // 4*256*256*16 chunks of 8ch
    if (idx >= 4 * 256 * 256 * 16) return;
    int cc = idx & 15;
    int pos = idx >> 4;
    int x = pos & 255, y = (pos >> 8) & 255, b = pos >> 16;
    const float4* s4 = (const float4*)(in + (size_t)idx * 8);
    float4 a = s4[0], bb = s4[1];
    u16 tmp[8];
    tmp[0] = f2u(a.x);  tmp[1] = f2u(a.y);  tmp[2] = f2u(a.z);  tmp[3] = f2u(a.w);
    tmp[4] = f2u(bb.x); tmp[5] = f2u(bb.y); tmp[6] = f2u(bb.z); tmp[7] = f2u(bb.w);
    *(uint4*)&out[(((b * 258 + y + 1) * 258) + x + 1) * 128 + cc * 8] = *(uint4*)tmp;
}

// classification head: mean -> fc1 -> fc2 -> fc3 -> softmax/argmax  (all fp32)
__global__ __launch_bounds__(256)
void cls_head(const float* __restrict__ feat5,
              const float* fc1w, const float* fc1b,
              const float* fc2w, const float* fc2b,
              const float* fc3w, const float* fc3b,
              float* __restrict__ pred_out, int* __restrict__ cls_out)
{
    int b = blockIdx.x, t = threadIdx.x;
    __shared__ float g[256], h1[256], h2[256], lg[3];
    const float* base = feat5 + b * 65536;
    float s = 0.f;
    for (int p = 0; p < 256; ++p) s += base[p * 256 + t];
    g[t] = s * (1.f / 256.f);
    __syncthreads();
    float a = fc1b[t];
    for (int k = 0; k < 256; ++k) a += g[k] * fc1w[k * 256 + t];
    h1[t] = fmaxf(a, 0.f);
    __syncthreads();
    a = fc2b[t];
    for (int k = 0; k < 256; ++k) a += h1[k] * fc2w[k * 256 + t];
    h2[t] = fmaxf(a, 0.f);
    __syncthreads();
    if (t < 3) {
        float l = fc3b[t];
        for (int k = 0; k < 256; ++k) l += h2[k] * fc3w[k * 3 + t];
        lg[t] = l;
    }
    __syncthreads();
    if (t == 0) {
        float m = fmaxf(lg[0], fmaxf(lg[1], lg[2]));
        float e0 = expf(lg[0] - m), e1 = expf(lg[1] - m), e2 = expf(lg[2] - m);
        float inv = 1.f / (e0 + e1 + e2);
        pred_out[b * 3 + 0] = e0 * inv;
        pred_out[b * 3 + 1] = e1 * inv;
        pred_out[b * 3 + 2] = e2 * inv;
        int best = 0;
        if (lg[1] > lg[best]) best = 1;
        if (lg[2] > lg[best]) best = 2;
        cls_out[b] = best;
    }
}

// bilinear crop: fp32 feat0 [4,512,512,64] + fp32 boxes -> bf16 cropsp [256][34][34][64]
__global__ __launch_bounds__(256)
void crop_kernel(const float* __restrict__ feat0, const float* __restrict__ boxes,
                 u16* __restrict__ cropsp)
{
    int gid = blockIdx.x;           // n*32 + oy
    int oy = gid & 31;
    int n = gid >> 5;
    int b = n >> 6;
    const float* bx = boxes + n * 4;
    float y1 = bx[0], x1 = bx[1], y2 = bx[2], x2 = bx[3];
    float ty = (float)oy * (1.f / 31.f);
    float ys = y1 * 511.f + (ty * (y2 - y1)) * 511.f;
    int y0i = (int)floorf(ys);
    y0i = y0i < 0 ? 0 : (y0i > 510 ? 510 : y0i);
    float wy = ys - (float)y0i;
    int t = threadIdx.x;
    int c = t & 63;
    int xg = t >> 6;
    const float* r0 = feat0 + ((size_t)(b * 512 + y0i) * 512) * 64;
    for (int ox = xg; ox < 32; ox += 4) {
        float tx = (float)ox * (1.f / 31.f);
        float xs = x1 * 511.f + (tx * (x2 - x1)) * 511.f;
        int x0i = (int)floorf(xs);
        x0i = x0i < 0 ? 0 : (x0i > 510 ? 510 : x0i);
        float wx = xs - (float)x0i;
        float v00 = r0[x0i * 64 + c];
        float v01 = r0[(x0i + 1) * 64 + c];
        float v10 = r0[32768 + x0i * 64 + c];
        float v11 = r0[32768 + (x0i + 1) * 64 + c];
        float ca = v00 * (1.f - wy) + v10 * wy;
        float cb = v01 * (1.f - wy) + v11 * wy;
        float val = ca * (1.f - wx) + cb * wx;
        cropsp[((n * 34 + oy + 1) * 34 + ox + 1) * 64 + c] = f2u(val);
    }
}

// per-class gather of bf16 reg/wt head -> fp32 offsets, sizes, weights
__global__ void reg_gather(const u16* __restrict__ head15, const int* __restrict__ cls,
                           float* __restrict__ out)
{
    int idx = blockIdx.x * 256 + threadIdx.x;   // 4*256*256
    if (idx >= 262144) return;
    int b = idx >> 16;
    int cl = cls[b];
    int c4 = cl * 4;
    const u16* p = head15 + (long)idx * 16;
    out[idx * 2 + 0] = u2f(p[c4]);
    out[idx * 2 + 1] = u2f(p[c4 + 1]);
    out[524288 + idx * 2 + 0] = u2f(p[c4 + 2]);
    out[524288 + idx * 2 + 1] = u2f(p[c4 + 3]);
    out[1048576 + idx] = u2f(p[12 + cl]);
}

__global__ void seg_gather(const u16* __restrict__ seg16, const int* __restrict__ cls,
                           float* __restrict__ out)
{
    int idx = blockIdx.x * 256 + threadIdx.x;   // 256*32*32
    if (idx >= 262144) return;
    int n = idx >> 10;
    out[idx] = u2f(seg16[(long)idx * 16 + cls[n >> 6]]);
}

// score head v2: 64 blocks x 4 boxes -> 4x less sd1w traffic, same fp32 math
__global__ __launch_bounds__(256)
void score_head2(const u16* __restrict__ s2p,
                 const float* sd1w, const float* sd1b,
                 const float* sd2w, const float* sd2b,
                 const float* sd3w, const float* sd3b,
                 const int* __restrict__ cls, float* __restrict__ out)
{
    int nb = blockIdx.x * 4;
    int t = threadIdx.x;
    __shared__ __align__(16) f32x4 pooled[6144];
    __shared__ float h1[4][256];
    __shared__ float h2[4][256];
    for (int q = 0; q < 24; ++q) {
        int o = t + 256 * q;
        int c = o % 96;
        int pw = o / 96;
        int wx = pw & 7, hy = pw >> 3;
        f32x4 v;
#pragma unroll
        for (int j = 0; j < 4; ++j) {
            const u16* sb = s2p + (long)(nb + j) * (34 * 34 * 96);
            float s = 0.f;
            for (int i = 0; i < 4; ++i)
                for (int jj = 0; jj < 4; ++jj)
                    s += u2f(sb[((1 + hy * 4 + i) * 34 + (1 + wx * 4 + jj)) * 96 + c]);
            v[j] = s * 0.0625f;
        }
        pooled[o] = v;
    }
    __syncthreads();
    float a0 = sd1b[t], a1 = a0, a2 = a0, a3 = a0;
    for (int k = 0; k < 6144; ++k) {
        float w = sd1w[k * 256 + t];
        f32x4 pv = pooled[k];
        a0 += pv[0] * w; a1 += pv[1] * w; a2 += pv[2] * w; a3 += pv[3] * w;
    }
    h1[0][t] = fmaxf(a0, 0.f); h1[1][t] = fmaxf(a1, 0.f);
    h1[2][t] = fmaxf(a2, 0.f); h1[3][t] = fmaxf(a3, 0.f);
    __syncthreads();
    a0 = sd2b[t]; a1 = a0; a2 = a0; a3 = a0;
    for (int k = 0; k < 256; ++k) {
        float w = sd2w[k * 256 + t];
        a0 += h1[0][k] * w; a1 += h1[1][k] * w; a2 += h1[2][k] * w; a3 += h1[3][k] * w;
    }
    h2[0][t] = fmaxf(a0, 0.f); h2[1][t] = fmaxf(a1, 0.f);
    h2[2][t] = fmaxf(a2, 0.f); h2[3][t] = fmaxf(a3, 0.f);
    __syncthreads();
    if (t < 4) {
        int cl = cls[(nb + t) >> 6];
        float s = sd3b[cl];
        for (int k = 0; k < 256; ++k) s += h2[t][k] * sd3w[k * 3 + cl];
        out[nb + t] = s;
    }
}

// ---------------------------------------------------------------------------
extern "C" void kernel_launch(void* const* d_in, const int* in_sizes, int n_in,
                              void* d_out, int out_size, void* d_ws, size_t ws_size,
                              hipStream_t stream)
{
    const float* feat0 = (const float*)d_in[0];
    const float* feat1 = (const float*)d_in[1];
    const float* feat5 = (const float*)d_in[2];
    const float* boxes = (const float*)d_in[3];
    const float* cb1_w = (const float*)d_in[4];  const float* cb1_b = (const float*)d_in[5];
    const float* cb2_w = (const float*)d_in[6];  const float* cb2_b = (const float*)d_in[7];
    const float* reg_w = (const float*)d_in[8];  const float* reg_b = (const float*)d_in[9];
    const float* wt_w  = (const float*)d_in[10]; const float* wt_b  = (const float*)d_in[11];
    const float* fc1_w = (const float*)d_in[12]; const float* fc1_b = (const float*)d_in[13];
    const float* fc2_w = (const float*)d_in[14]; const float* fc2_b = (const float*)d_in[15];
    const float* fc3_w = (const float*)d_in[16]; const float* fc3_b = (const float*)d_in[17];
    const float* sc1_w = (const float*)d_in[18]; const float* sc1_b = (const float*)d_in[19];
    const float* sc2_w = (const float*)d_in[20]; const float* sc2_b = (const float*)d_in[21];
    const float* so_w  = (const float*)d_in[22]; const float* so_b  = (const float*)d_in[23];
    const float* sd1_w = (const float*)d_in[24]; const float* sd1_b = (const float*)d_in[25];
    const float* sd2_w = (const float*)d_in[26]; const float* sd2_b = (const float*)d_in[27];
    const float* sd3_w = (const float*)d_in[28]; const float* sd3_b = (const float*)d_in[29];

    char* ws = (char*)d_ws;
    size_t off = 0;
    auto alloc = [&](size_t bytes) -> char* {
        char* p = ws + off;
        off += (bytes + 255) & ~(size_t)255;
        return p;
    };
    u16* pad1   = (u16*)alloc(68161536);   // region0: later reused as cropsp
    u16* x1p    = (u16*)alloc(136323072);  // region1: later reused as s1p+s2p
    u16* x2p    = (u16*)alloc(136323072);
    u16* head15 = (u16*)alloc(8388608);
    u16* seg16  = (u16*)alloc(8388608);
    u16* cb1T   = (u16*)alloc(589824);
    u16* cb2T   = (u16*)alloc(1179648);
    u16* headT  = (u16*)alloc(73728);
    float* headB = (float*)alloc(64);
    u16* sc1T   = (u16*)alloc(147456);
    u16* sc2T   = (u16*)alloc(221184);
    u16* soT    = (u16*)alloc(36864);      // [9][16][128] swizzled
    float* soB  = (float*)alloc(64);
    int* cls    = (int*)alloc(16);
    u16* cropsp = pad1;                    // 37,879,808 B <= 68,161,536
    u16* s1p    = x1p;                     // 56,819,712 B
    u16* s2p    = x1p + 28409856;          // + 56,819,712 B (fits region1)
    float* d_o  = (float*)d_out;

    auto ring = [&](u16* buf, int n, int Hp, int Wp, int C) {
        int per = (2 * Wp + 2 * (Hp - 2)) * C;
        long tot = (long)per * n;
        zero_ring<<<(int)((tot + 255) / 256), 256, 0, stream>>>(
            buf, Hp, Wp, C, (long)Hp * Wp * C, per, tot);
    };

    // weight transposes (tiny)
    transpose_w<<<(9*256*128 + 255)/256, 256, 0, stream>>>(cb1_w, cb1T, 128, 256, 256);
    transpose_w<<<(9*256*256 + 255)/256, 256, 0, stream>>>(cb2_w, cb2T, 256, 256, 256);
    transpose_w<<<(9*128*64  + 255)/256, 256, 0, stream>>>(sc1_w, sc1T, 64, 96, 128);
    transpose_w<<<(9*128*96  + 255)/256, 256, 0, stream>>>(sc2_w, sc2T, 96, 96, 128);
    transpose_n16_swz<256><<<144, 256, 0, stream>>>(reg_w, wt_w, reg_b, wt_b,
                                                    headT, headB, 256, 12, 3);
    transpose_n16_swz<128><<<72, 256, 0, stream>>>(so_w, (const float*)nullptr,
                                                   so_b, (const float*)nullptr,
                                                   soT, soB, 96, 3, 0);

    // classification branch (also produces cls[] used by all gathers)
    cls_head<<<4, 256, 0, stream>>>(feat5, fc1_w, fc1_b, fc2_w, fc2_b, fc3_w, fc3_b,
                                    d_o + 1310720, cls);

    // regression branch
    ring(pad1, 4, 258, 258, 128);
    cvt_pad<<<16384, 256, 0, stream>>>(feat1, pad1);
    ring(x1p, 4, 258, 258, 256);
    conv3x3_8ph<2, 7><<<1024, 512, 0, stream>>>(
        pad1, cb1T, cb1_b, x1p, 128, 258, 258L*258*128, 256, 2,
        256, 258*256, 258L*258*256, 259*256, 1);
    ring(x2p, 4, 258, 258, 256);
    conv3x3_8ph<4, 7><<<1024, 512, 0, stream>>>(
        x1p, cb2T, cb2_b, x2p, 256, 258, 258L*258*256, 256, 2,
        256, 258*256, 258L*258*256, 259*256, 1);
    conv3x3_n16<4, 64, 256, 256, 8><<<1024, 256, 0, stream>>>(
        x2p, headT, headB, head15, 258L*258*256, 258, 256, 4,
        256L*256*16, 256*16);
    reg_gather<<<1024, 256, 0, stream>>>(head15, cls, d_o);

    // segmentation branch (reuses region0/region1 after convs above)
    ring(cropsp, 256, 34, 34, 64);
    crop_kernel<<<8192, 256, 0, stream>>>(feat0, boxes, cropsp);
    ring(s1p, 256, 34, 34, 96);
    conv3x3_mfma<128,2,2,5><<<dim3(2048,1), 256, 0, stream>>>(
        cropsp, sc1T, sc1_b, s1p, 64, 96, 128, 34, 34*34*64, 8, 1,
        96, 34*96, 34*34*96, 35*96, 2, 1);
    ring(s2p, 256, 34, 34, 96);
    conv3x3_mfma<128,2,2,5><<<dim3(2048,1), 256, 0, stream>>>(
        s1p, sc2T, sc2_b, s2p, 96, 96, 128, 34, 34*34*96, 8, 1,
        96, 34*96, 34*34*96, 35*96, 3, 1);
    conv3x3_n16<8, 32, 96, 128, 3><<<1024, 256, 0, stream>>>(
        s2p, soT, soB, seg16, 34L*34*96, 34, 4, 1,
        32L*32*16, 32*16);
    seg_gather<<<1024, 256, 0, stream>>>(seg16, cls, d_o + 1310732);
    score_head2<<<64, 256, 0, stream>>>(s2p, sd1_w, sd1_b, sd2_w, sd2_b, sd3_w, sd3_b,
                                        cls, d_o + 1572876);
    (void)in_sizes; (void)n_in; (void)out_size; (void)ws_size;
}